// Round 9
// baseline (3112.442 us; speedup 1.0000x reference)
//
#include <hip/hip_runtime.h>
#include <math.h>

// Problem constants: L=512 (batch/spatial), T=96, C=H=150, K=5
#define LB     512
#define TSTEPS 96
#define CIN    150
#define HDIM   150
#define KW     5
#define CO3    450   // 3*H
// gru tiling
#define NBT    16    // b-tiles
#define NJT    15    // j-tiles
#define BROWS  32    // rows per b-tile
#define JW     10    // j per j-tile (30 co = 3 gates x 10 j)
#define NCH    15    // ci chunks
#define CICH   10    // ci per chunk
#define HROWS  36    // staged rows = 32 + 2x2 halo
#define HPAD   152   // LDS row stride (floats)
#define CNTSTR 32    // ints per counter slot (128 B)
#define PARTR  33    // padded row dim of part: 990%32=30 -> ch stays in bank idx

// fast device math: v_exp_f32-based sigmoid / tanh (rel err ~2^-21)
__device__ __forceinline__ float fsigmoid(float x) {
    return __builtin_amdgcn_rcpf(1.f + __expf(-x));
}
__device__ __forceinline__ float ftanh(float x) {
    return fmaf(2.f, __builtin_amdgcn_rcpf(1.f + __expf(-2.f * x)), -1.f);
}

// coherent (agent-scope) ops for cross-XCD h traffic; ordering via the
// producer-side __syncthreads vmcnt(0) drain before the flag add.
__device__ __forceinline__ float h_load(const float* p) {
    return __hip_atomic_load(p, __ATOMIC_RELAXED, __HIP_MEMORY_SCOPE_AGENT);
}
__device__ __forceinline__ void h_store(float* p, float v) {
    __hip_atomic_store(p, v, __ATOMIC_RELAXED, __HIP_MEMORY_SCOPE_AGENT);
}

// ---------------------------------------------------------------------------
// xi conv (unchanged; measured 445 us, VALUBusy 81%, ~74 TF)
// ---------------------------------------------------------------------------
__global__ __launch_bounds__(256) void xi_conv_kernel(
    const float* __restrict__ src, long srcB, long srcT,
    const float* __restrict__ Wi, const float* __restrict__ bias,
    float* __restrict__ xi)
{
    __shared__ __align__(16) float xsh[CIN][20];
    const int b0  = blockIdx.x * 16;
    const int t   = blockIdx.y;
    const int tid = threadIdx.x;

    for (int idx = tid; idx < 20 * CIN; idx += 256) {
        int row = idx / CIN;
        int ci  = idx - row * CIN;
        int bp  = b0 + row - 2;
        float v = 0.f;
        if (bp >= 0 && bp < LB) v = src[(long)bp * srcB + (long)t * srcT + ci];
        xsh[ci][row] = v;
    }
    __syncthreads();

    if (tid < 225) {
        const int co = 2 * tid;
        float acc0[16], acc1[16];
        #pragma unroll
        for (int b = 0; b < 16; ++b) { acc0[b] = 0.f; acc1[b] = 0.f; }

        for (int ci = 0; ci < CIN; ++ci) {
            float4 a0 = *(const float4*)&xsh[ci][0];
            float4 a1 = *(const float4*)&xsh[ci][4];
            float4 a2 = *(const float4*)&xsh[ci][8];
            float4 a3 = *(const float4*)&xsh[ci][12];
            float4 a4 = *(const float4*)&xsh[ci][16];
            float xr[20];
            xr[0]=a0.x; xr[1]=a0.y; xr[2]=a0.z; xr[3]=a0.w;
            xr[4]=a1.x; xr[5]=a1.y; xr[6]=a1.z; xr[7]=a1.w;
            xr[8]=a2.x; xr[9]=a2.y; xr[10]=a2.z; xr[11]=a2.w;
            xr[12]=a3.x; xr[13]=a3.y; xr[14]=a3.z; xr[15]=a3.w;
            xr[16]=a4.x; xr[17]=a4.y; xr[18]=a4.z; xr[19]=a4.w;

            #pragma unroll
            for (int k = 0; k < KW; ++k) {
                const float2 w = *(const float2*)&Wi[((long)(k * CIN + ci)) * CO3 + co];
                #pragma unroll
                for (int b = 0; b < 16; ++b) {
                    float x = xr[b + k];
                    acc0[b] = fmaf(w.x, x, acc0[b]);
                    acc1[b] = fmaf(w.y, x, acc1[b]);
                }
            }
        }

        const float2 bia = *(const float2*)&bias[co];
        float* xo = xi + ((long)t * LB + b0) * CO3 + co;
        #pragma unroll
        for (int b = 0; b < 16; ++b) {
            float2 o; o.x = acc0[b] + bia.x; o.y = acc1[b] + bia.y;
            *(float2*)&xo[(long)b * CO3] = o;
        }
    }
}

// ---------------------------------------------------------------------------
// Persistent GRU pipeline, halo-split edition.
// Phase order hides neighbor latency behind the own-rows conv:
//   P0 poll own-bt flag -> P1 stage own 32 rows (+xi prefetch)
//   -> P2 conv with own rows only (boundary rows partial)
//   -> P3 poll bt+-1 (flags are ~5us old by now) + stage 4 halo rows
//   -> P4 halo-correction conv (6 weight-terms)
//   -> P5 reduce + gates (+halo partials on rows 0,1,30,31) -> store, flag++.
// part padded [15][33][30] (kills the 3-way ch-bank alias: 990%32=30).
// ---------------------------------------------------------------------------
__global__ __launch_bounds__(512, 1) void gru_seq_kernel(
    const float* __restrict__ Wh,
    const float* __restrict__ xi,
    float* __restrict__ ybase,
    long yT, long bS,
    int* __restrict__ cnt)
{
    __shared__ __align__(16) float hsh[HROWS][HPAD];      // 21.9 KB [row][ci]
    __shared__ float part[NCH][PARTR][3 * JW];            // 59.4 KB
    __shared__ float parth[NCH][4][33];                   // 7.9 KB halo partials

    const int blk = blockIdx.x;
    const int bt  = blk / NJT;
    const int jt  = blk - bt * NJT;
    const int b0  = bt * BROWS;
    const int j0  = jt * JW;
    const int tid = threadIdx.x;

    const bool act = (tid < NCH * 3 * JW);   // 450 conv threads
    const int  c   = tid % (3 * JW);
    const int  ch  = tid / (3 * JW);
    const int  g   = c / JW;
    const int  jl  = c - g * JW;
    const int  co  = g * HDIM + j0 + jl;
    const int  ci0 = ch * CICH;

    const bool gthr = (tid < BROWS * JW);    // 320 gate threads
    const int  grow = tid / JW;
    const int  gj   = tid - grow * JW;
    const bool bdry = gthr && (grow < 2 || grow >= 30);
    const int  rrb  = (grow < 2) ? grow : grow - 28;   // parth slot

    // ---- one-time: weights into registers ----
    float w[KW][CICH];
    if (act) {
        #pragma unroll
        for (int k = 0; k < KW; ++k)
            #pragma unroll
            for (int i = 0; i < CICH; ++i)
                w[k][i] = Wh[((long)(k * CIN + ci0 + i)) * CO3 + co];
    }

    for (int t = 0; t < TSTEPS; ++t) {
        // ---- P0: own-bt flag (all 15 j-blocks of bt wrote h(t-1) rows) ----
        if (t > 0 && tid == 0) {
            const int tgt = NJT * t;
            while (__hip_atomic_load(&cnt[bt * CNTSTR], __ATOMIC_RELAXED,
                                     __HIP_MEMORY_SCOPE_AGENT) < tgt)
                __builtin_amdgcn_s_sleep(1);
        }
        __syncthreads();

        // ---- P1: xi prefetch + stage own rows (b0..b0+31 -> staged 2..33) ----
        float pxr = 0.f, pxz = 0.f, pxn = 0.f;
        if (gthr) {
            const float* xp = xi + ((long)t * LB + b0 + grow) * CO3 + j0 + gj;
            pxr = xp[0];
            pxz = xp[HDIM];
            pxn = xp[2 * HDIM];
        }
        if (t > 0) {
            const float* hsrc = ybase + (long)(t - 1) * yT;
            float v[10];
            #pragma unroll
            for (int it = 0; it < 10; ++it) {
                int idx = tid + it * 512;
                int ci2 = (idx < BROWS * CIN) ? idx : (BROWS * CIN - 1);
                int row = ci2 / CIN, ci = ci2 - row * CIN;
                v[it] = h_load(&hsrc[(long)(b0 + row) * bS + ci]);  // always in-range
            }
            #pragma unroll
            for (int it = 0; it < 10; ++it) {
                int idx = tid + it * 512;
                if (idx < BROWS * CIN) {
                    int row = idx / CIN, ci = idx - row * CIN;
                    hsh[row + 2][ci] = v[it];
                }
            }
        } else {
            for (int idx = tid; idx < HROWS * CIN; idx += 512)
                hsh[idx / CIN][idx % CIN] = 0.f;
        }
        __syncthreads();

        // ---- P2: conv over OWN staged rows 2..33 (boundary outputs partial) ----
        if (act) {
            float acc[BROWS];
            #pragma unroll
            for (int r = 0; r < BROWS; ++r) acc[r] = 0.f;
            #pragma unroll
            for (int p = 0; p < CICH / 2; ++p) {
                #pragma unroll
                for (int row = 2; row < 34; ++row) {
                    float2 h2 = *(const float2*)&hsh[row][ci0 + 2 * p];
                    #pragma unroll
                    for (int k = 0; k < KW; ++k) {
                        const int r = row - k;
                        if (r >= 0 && r < BROWS) {
                            acc[r] = fmaf(w[k][2 * p],     h2.x, acc[r]);
                            acc[r] = fmaf(w[k][2 * p + 1], h2.y, acc[r]);
                        }
                    }
                }
            }
            #pragma unroll
            for (int r = 0; r < BROWS; ++r) part[ch][r][c] = acc[r];
        }

        // ---- P3: neighbor flags (set ~5us ago -> near-instant) + halo stage ----
        if (t > 0 && tid < 2) {
            const int x = bt + (tid ? 1 : -1);
            if (x >= 0 && x < NBT) {
                const int tgt = NJT * t;
                while (__hip_atomic_load(&cnt[x * CNTSTR], __ATOMIC_RELAXED,
                                         __HIP_MEMORY_SCOPE_AGENT) < tgt)
                    __builtin_amdgcn_s_sleep(1);
            }
        }
        __syncthreads();                     // part done + neighbor flags seen
        if (t > 0 && tid < 300) {
            const float* hsrc = ybase + (long)(t - 1) * yT;
            int e0 = tid, e1 = tid + 300;    // 600 halo elems: 4 rows x 150
            int h0r = e0 / CIN, c0_ = e0 - h0r * CIN;
            int h1r = e1 / CIN, c1_ = e1 - h1r * CIN;
            int s0 = (h0r < 2) ? h0r : h0r + 32;     // staged rows 0,1,34,35
            int s1 = (h1r < 2) ? h1r : h1r + 32;
            int g0 = b0 - 2 + s0, g1 = b0 - 2 + s1;
            int g0c = g0 < 0 ? 0 : (g0 > LB - 1 ? LB - 1 : g0);
            int g1c = g1 < 0 ? 0 : (g1 > LB - 1 ? LB - 1 : g1);
            float va = h_load(&hsrc[(long)g0c * bS + c0_]);
            float vb = h_load(&hsrc[(long)g1c * bS + c1_]);
            hsh[s0][c0_] = (g0 >= 0 && g0 < LB) ? va : 0.f;
            hsh[s1][c1_] = (g1 >= 0 && g1 < LB) ? vb : 0.f;
        }
        __syncthreads();

        // ---- P4: halo-correction conv (staged rows 0,1,34,35) ----
        if (act) {
            float a4[4] = {0.f, 0.f, 0.f, 0.f};   // outputs r=0,1,30,31
            #pragma unroll
            for (int p = 0; p < CICH / 2; ++p) {
                float2 h0 = *(const float2*)&hsh[0][ci0 + 2 * p];
                float2 h1 = *(const float2*)&hsh[1][ci0 + 2 * p];
                float2 h34 = *(const float2*)&hsh[34][ci0 + 2 * p];
                float2 h35 = *(const float2*)&hsh[35][ci0 + 2 * p];
                // r = srow - k: (s0,k0->r0) (s1,k0->r1) (s1,k1->r0)
                //               (s34,k4->r30) (s34,k3->r31) (s35,k4->r31)
                a4[0] = fmaf(w[0][2*p], h0.x,  fmaf(w[0][2*p+1], h0.y,  a4[0]));
                a4[0] = fmaf(w[1][2*p], h1.x,  fmaf(w[1][2*p+1], h1.y,  a4[0]));
                a4[1] = fmaf(w[0][2*p], h1.x,  fmaf(w[0][2*p+1], h1.y,  a4[1]));
                a4[2] = fmaf(w[4][2*p], h34.x, fmaf(w[4][2*p+1], h34.y, a4[2]));
                a4[3] = fmaf(w[3][2*p], h34.x, fmaf(w[3][2*p+1], h34.y, a4[3]));
                a4[3] = fmaf(w[4][2*p], h35.x, fmaf(w[4][2*p+1], h35.y, a4[3]));
            }
            #pragma unroll
            for (int rr = 0; rr < 4; ++rr) parth[ch][rr][c] = a4[rr];
        }
        __syncthreads();

        // ---- P5: reduce + gates (+halo partials on boundary rows) + store ----
        if (gthr) {
            float hr = 0.f, hz = 0.f, hn = 0.f;
            #pragma unroll
            for (int s = 0; s < NCH; ++s) {
                hr += part[s][grow][gj];
                hz += part[s][grow][JW + gj];
                hn += part[s][grow][2 * JW + gj];
            }
            if (bdry) {
                #pragma unroll
                for (int s = 0; s < NCH; ++s) {
                    hr += parth[s][rrb][gj];
                    hz += parth[s][rrb][JW + gj];
                    hn += parth[s][rrb][2 * JW + gj];
                }
            }
            const int b = b0 + grow;
            float r  = fsigmoid(pxr + hr);
            float z  = fsigmoid(pxz + hz);
            float n  = ftanh(fmaf(r, hn, pxn));
            float hp = hsh[grow + 2][j0 + gj];       // h(t-1)[b][j], zeros at t=0
            h_store(&ybase[(long)t * yT + (long)b * bS + j0 + gj],
                    fmaf(z, hp - n, n));
        }
        __syncthreads();   // drains vmcnt(0): h(t) stores acked before flag add

        if (tid == 0)
            __hip_atomic_fetch_add(&cnt[bt * CNTSTR], 1, __ATOMIC_RELAXED,
                                   __HIP_MEMORY_SCOPE_AGENT);
    }
}

// ---------------------------------------------------------------------------
__global__ void zero_cnt_kernel(int* cnt) {
    for (int i = threadIdx.x; i < 2 * NBT * CNTSTR; i += 256) cnt[i] = 0;
}

// ---------------------------------------------------------------------------
extern "C" void kernel_launch(void* const* d_in, const int* in_sizes, int n_in,
                              void* d_out, int out_size, void* d_ws, size_t ws_size,
                              hipStream_t stream) {
    const float* xs  = (const float*)d_in[0];
    const float* Wi0 = (const float*)d_in[1];
    const float* bi0 = (const float*)d_in[2];
    const float* Wh0 = (const float*)d_in[3];
    const float* Wi1 = (const float*)d_in[4];
    const float* bi1 = (const float*)d_in[5];
    const float* Wh1 = (const float*)d_in[6];
    float* out = (float*)d_out;

    // ws layout: [cnt 2*16*128B = 4 KB | xi 88.5 MB | ys0 29.5 MB]
    int*   cnt = (int*)d_ws;
    float* xi  = (float*)((char*)d_ws + 4096);
    float* ys0 = xi + (size_t)TSTEPS * LB * CO3;

    hipLaunchKernelGGL(zero_cnt_kernel, dim3(1), dim3(256), 0, stream, cnt);

    dim3 gxi(32, TSTEPS);

    // ---- layer 0 ----
    hipLaunchKernelGGL(xi_conv_kernel, gxi, dim3(256), 0, stream,
                       xs, (long)(TSTEPS * CIN), (long)CIN, Wi0, bi0, xi);
    {
        const float* Wh = Wh0; const float* xip = xi; float* yb = ys0;
        long yT = (long)LB * HDIM;   // ys0 (T,B,H)
        long bS = (long)HDIM;
        int* c0 = cnt;
        void* args[] = { (void*)&Wh, (void*)&xip, (void*)&yb,
                         (void*)&yT, (void*)&bS, (void*)&c0 };
        hipLaunchCooperativeKernel((void*)gru_seq_kernel, dim3(NBT * NJT),
                                   dim3(512), args, 0, stream);
    }

    // ---- layer 1 ----
    hipLaunchKernelGGL(xi_conv_kernel, gxi, dim3(256), 0, stream,
                       ys0, (long)HDIM, (long)(LB * HDIM), Wi1, bi1, xi);
    {
        const float* Wh = Wh1; const float* xip = xi; float* yb = out;
        long yT = (long)HDIM;             // out (B,T,H): t slice offset = t*H
        long bS = (long)(TSTEPS * HDIM);  // b stride = T*H
        int* c1 = cnt + NBT * CNTSTR;
        void* args[] = { (void*)&Wh, (void*)&xip, (void*)&yb,
                         (void*)&yT, (void*)&bS, (void*)&c1 };
        hipLaunchCooperativeKernel((void*)gru_seq_kernel, dim3(NBT * NJT),
                                   dim3(512), args, 0, stream);
    }
}